// Round 9
// baseline (325.329 us; speedup 1.0000x reference)
//
#include <hip/hip_runtime.h>
#include <cstdint>
#include <cmath>

typedef __bf16 bf16x8 __attribute__((ext_vector_type(8)));
typedef __bf16 bf16x4 __attribute__((ext_vector_type(4)));
typedef float  f32x4  __attribute__((ext_vector_type(4)));

#define DEVI __device__ __forceinline__

#define SEQ 4096
#define NH 8
#define NKV 4
#define HD 256
#define WIN 1024

DEVI void gload16(const void* g, void* l) {
  __builtin_amdgcn_global_load_lds((const __attribute__((address_space(1))) void*)g,
                                   (__attribute__((address_space(3))) void*)l,
                                   16, 0, 0);
}

DEVI bf16x8 ld8f(const float* p) {
  const f32x4 a = *(const f32x4*)p;
  const f32x4 b = *(const f32x4*)(p + 4);
  bf16x8 r;
#pragma unroll
  for (int j = 0; j < 4; ++j) { r[j] = (__bf16)a[j]; r[4 + j] = (__bf16)b[j]; }
  return r;
}

DEVI void st1(float* p, float v)  { *p = v; }
DEVI void st1(__bf16* p, float v) { *p = (__bf16)v; }

// ---------------------------------------------------------------------------
// fp32 -> bf16 conversion, grid-stride x4 (2560 blocks).
// Wq/Wk/Wv concatenated into one 4096x2048 buffer.
// ---------------------------------------------------------------------------
__global__ __launch_bounds__(256)
void cvt_all(const float* __restrict__ x,  const float* __restrict__ wq,
             const float* __restrict__ wk, const float* __restrict__ wv,
             const float* __restrict__ wo,
             __bf16* __restrict__ xb, __bf16* __restrict__ wqkvb,
             __bf16* __restrict__ wob) {
#pragma unroll
  for (int k = 0; k < 4; ++k) {
    const size_t g = (size_t)blockIdx.x * 256 + threadIdx.x + (size_t)k * 655360;
    const float* src; __bf16* dst; size_t off;
    if      (g < 1048576) { src = x;  dst = xb;               off = g; }
    else if (g < 1572864) { src = wq; dst = wqkvb;            off = g - 1048576; }
    else if (g < 1835008) { src = wk; dst = wqkvb + 4194304;  off = g - 1572864; }
    else if (g < 2097152) { src = wv; dst = wqkvb + 6291456;  off = g - 1835008; }
    else                  { src = wo; dst = wob;              off = g - 2097152; }
    *(bf16x8*)(dst + off * 8) = ld8f(src + off * 8);
  }
}

// ---------------------------------------------------------------------------
// GEMM: C[M][N] = A[M][K] * B[N][K]^T, bf16 in, f32 acc, BK=64 chunk-major
// (As2[2][128][32]: staging linear for global_load_lds, 64B fragment rows).
// If vt != nullptr, column-blocks with col0 >= 3072 write TRANSPOSED bf16
// to vt[(n-3072)*SEQ + t] (V-slice) instead of C — fuses the V transpose.
// ---------------------------------------------------------------------------
template <typename TC>
__global__ __launch_bounds__(256, 2)
void gemm_bt(const __bf16* __restrict__ A, const __bf16* __restrict__ B,
             TC* __restrict__ C, __bf16* __restrict__ vt, int N, int K) {
  __shared__ __bf16 As2[2][128][32];   // 16 KB  [k-chunk][row][dim8]
  __shared__ __bf16 Bs2[2][128][32];   // 16 KB
  const int tid  = threadIdx.x;
  const int lane = tid & 63;
  const int wave = tid >> 6;
  const int l15  = lane & 15;
  const int l4   = lane >> 4;

  const int lin  = blockIdx.x + gridDim.x * blockIdx.y;
  const int xcd  = lin & 7;
  const int kk   = lin >> 3;
  const int row0 = (xcd * 4 + (kk & 3)) * 128;
  const int col0 = (kk >> 2) * 128;

  const int wm   = (wave >> 1) * 64;
  const int wn   = (wave & 1) * 64;

  f32x4 acc[4][4] = {};

  for (int k0 = 0; k0 < K; k0 += 64) {
    __syncthreads();
#pragma unroll
    for (int i = 0; i < 4; ++i) {
      const int s  = i * 256 + tid;
      const int ch = s >> 9, r = (s >> 2) & 127, c4 = s & 3;
      gload16(A + (size_t)(row0 + r) * K + k0 + ch * 32 + c4 * 8,
              (char*)As2 + (i * 256 + wave * 64) * 16);
    }
#pragma unroll
    for (int i = 0; i < 4; ++i) {
      const int s  = i * 256 + tid;
      const int ch = s >> 9, r = (s >> 2) & 127, c4 = s & 3;
      gload16(B + (size_t)(col0 + r) * K + k0 + ch * 32 + c4 * 8,
              (char*)Bs2 + (i * 256 + wave * 64) * 16);
    }
    __syncthreads();
#pragma unroll
    for (int ch = 0; ch < 2; ++ch) {
      bf16x8 af[4], bfr[4];
#pragma unroll
      for (int i = 0; i < 4; ++i)
        af[i] = *(const bf16x8*)&As2[ch][wm + i * 16 + l15][l4 * 8];
#pragma unroll
      for (int i = 0; i < 4; ++i)
        bfr[i] = *(const bf16x8*)&Bs2[ch][wn + i * 16 + l15][l4 * 8];
#pragma unroll
      for (int i = 0; i < 4; ++i)
#pragma unroll
        for (int j = 0; j < 4; ++j)
          acc[i][j] = __builtin_amdgcn_mfma_f32_16x16x32_bf16(af[i], bfr[j], acc[i][j], 0, 0, 0);
    }
  }

  // C/D layout: col = lane&15, row = (lane>>4)*4 + reg   [m89/m91 verified]
  if (vt != nullptr && col0 >= 3072) {
    // V-block: write transposed to vt[(n-3072)][t], packing reg 0..3 (4
    // consecutive t) into one 8 B store per (i,j).
#pragma unroll
    for (int i = 0; i < 4; ++i) {
      const int t0 = row0 + wm + i * 16 + l4 * 4;
#pragma unroll
      for (int j = 0; j < 4; ++j) {
        const int nv = col0 - 3072 + wn + l15 + j * 16;
        bf16x4 v;
#pragma unroll
        for (int reg = 0; reg < 4; ++reg) v[reg] = (__bf16)acc[i][j][reg];
        *(bf16x4*)(vt + (size_t)nv * SEQ + t0) = v;
      }
    }
  } else {
#pragma unroll
    for (int i = 0; i < 4; ++i) {
#pragma unroll
      for (int reg = 0; reg < 4; ++reg) {
        const int row = row0 + wm + i * 16 + l4 * 4 + reg;
        TC* crow = C + (size_t)row * N + col0 + wn + l15;
#pragma unroll
        for (int j = 0; j < 4; ++j)
          st1(crow + j * 16, acc[i][j][reg]);
      }
    }
  }
}

// ---------------------------------------------------------------------------
// Per-head RMSNorm + RoPE, in place on qkv_ws cols 0..3071.
// 3072 blocks x 256 thr; each wave loops over 4 rows (16 rows/block).
// ---------------------------------------------------------------------------
__global__ __launch_bounds__(256)
void norm_rope(__bf16* __restrict__ qkv,
               const float* __restrict__ qw, const float* __restrict__ kw,
               const int* __restrict__ pos) {
  const int lane = threadIdx.x & 63;
  const int wave = threadIdx.x >> 6;
  const int d0   = lane * 4;
#pragma unroll
  for (int ri = 0; ri < 4; ++ri) {
    const int gw = blockIdx.x * 16 + wave * 4 + ri;
    __bf16* base; const float* w; int t;
    if (gw < SEQ * NH) {
      t = gw >> 3;
      base = qkv + (size_t)t * 4096 + (gw & 7) * HD;
      w = qw;
    } else {
      const int g = gw - SEQ * NH;
      t = g >> 2;
      base = qkv + (size_t)t * 4096 + 2048 + (g & 3) * HD;
      w = kw;
    }

    float v[4]; float ss = 0.f;
#pragma unroll
    for (int j = 0; j < 4; ++j) { v[j] = (float)base[d0 + j]; ss += v[j] * v[j]; }
#pragma unroll
    for (int off = 1; off < 64; off <<= 1) ss += __shfl_xor(ss, off);
    const float rms = rsqrtf(ss * (1.0f / 256.0f) + 1e-6f);
    const float p = (float)pos[t];

    float n[4];
#pragma unroll
    for (int j = 0; j < 4; ++j) n[j] = v[j] * rms * w[d0 + j];

    float outv[4];
#pragma unroll
    for (int e = 0; e < 4; e += 2) {
      const int i0 = d0 + e, i1 = i0 + 1;
      const float f0 = exp2f(-(float)(i0 & 127) * 0.103810253f);
      const float f1 = exp2f(-(float)(i1 & 127) * 0.103810253f);
      float s0, cc0, s1, cc1;
      sincosf(p * f0, &s0, &cc0);
      sincosf(p * f1, &s1, &cc1);
      outv[e]     = n[e] * cc0 - n[e + 1] * s0;
      outv[e + 1] = n[e + 1] * cc1 + n[e] * s1;
    }
#pragma unroll
    for (int j = 0; j < 4; ++j) base[d0 + j] = (__bf16)outv[j];
  }
}

// ---------------------------------------------------------------------------
// Sliding-window flash attention, fixed-max softmax, async LDS staging,
// wave-uniform all-visible fast path (interior tiles skip mask compares).
// Grid (64 q-tiles, 8 heads), 256 thr = 4 waves x 16 queries.
// ---------------------------------------------------------------------------
__global__ __launch_bounds__(256, 2)
void attn_fwd(const __bf16* __restrict__ qkv, const __bf16* __restrict__ Vt,
              __bf16* __restrict__ Y) {
  __shared__ __bf16 Ks2[8][64][32];    // 32768 B  [k-chunk][key][dim8]
  __shared__ __bf16 Vts2[2][256][32];  // 32768 B  [key-chunk][dim][key8]
  __shared__ __bf16 Ps[4][16][72];     //  9216 B  per-wave P
  const int tid  = threadIdx.x;
  const int lane = tid & 63;
  const int wave = tid >> 6;
  const int l15  = lane & 15;
  const int l4   = lane >> 4;
  const int q0   = blockIdx.x * 64;
  const int head = blockIdx.y;
  const int kvh  = head >> 1;
  const int qw   = q0 + wave * 16;

  // Q fragments: A[m=lane&15][k=(lane>>4)*8+j]; pre-scale 1/16 (exact pow2)
  bf16x8 qf[8];
  const __bf16* qrow = qkv + (size_t)(qw + l15) * 4096 + head * HD;
#pragma unroll
  for (int ks = 0; ks < 8; ++ks) {
    bf16x8 t = *(const bf16x8*)(qrow + ks * 32 + l4 * 8);
#pragma unroll
    for (int j = 0; j < 8; ++j) t[j] = (__bf16)((float)t[j] * 0.0625f);
    qf[ks] = t;
  }

  f32x4 o[16] = {};
  float l_run[4] = {0.f, 0.f, 0.f, 0.f};

  int lo = q0 - (WIN - 1); if (lo < 0) lo = 0;
  const int kt0 = lo >> 6;
  const int kt1 = (q0 + 63) >> 6;   // uniform across the block

  for (int kt = kt0; kt <= kt1; ++kt) {
    const int kb = kt * 64;
    __syncthreads();
#pragma unroll
    for (int i = 0; i < 8; ++i) {
      const int s = i * 256 + tid;
      gload16(qkv + (size_t)(kb + ((s >> 2) & 63)) * 4096 + 2048 + kvh * HD
                  + (s >> 8) * 32 + (s & 3) * 8,
              (char*)Ks2 + (i * 256 + wave * 64) * 16);
    }
#pragma unroll
    for (int i = 0; i < 8; ++i) {
      const int s = i * 256 + tid;
      gload16(Vt + ((size_t)kvh * HD + ((s >> 2) & 255)) * SEQ + kb
                 + (s >> 10) * 32 + (s & 3) * 8,
              (char*)Vts2 + (i * 256 + wave * 64) * 16);
    }
    __syncthreads();

    // S = (Q/16) K^T
    f32x4 s_acc[4] = {};
#pragma unroll
    for (int kn = 0; kn < 4; ++kn) {
#pragma unroll
      for (int ks = 0; ks < 8; ++ks) {
        bf16x8 kf = *(const bf16x8*)&Ks2[ks][kn * 16 + l15][l4 * 8];
        s_acc[kn] = __builtin_amdgcn_mfma_f32_16x16x32_bf16(qf[ks], kf, s_acc[kn], 0, 0, 0);
      }
    }

    // fixed-max softmax: p = exp(min(s,34)-34); masked -> 0
    // (post-RMSNorm |q|=|k|=16, RoPE growth <= sqrt2 => s <= 32 provably)
    // Wave-uniform fast path when the whole tile is inside the window.
    const bool allvis = (kb + 63 <= qw) && (kb >= qw - 1008);
    if (allvis) {
#pragma unroll
      for (int reg = 0; reg < 4; ++reg) {
        const int r = l4 * 4 + reg;
        float ps = 0.f;
#pragma unroll
        for (int kn = 0; kn < 4; ++kn) {
          const float p = __expf(fminf(s_acc[kn][reg], 34.f) - 34.f);
          ps += p;
          Ps[wave][r][kn * 16 + l15] = (__bf16)p;
        }
        l_run[reg] += ps;
      }
    } else {
#pragma unroll
      for (int reg = 0; reg < 4; ++reg) {
        const int r  = l4 * 4 + reg;
        const int qg = qw + r;
        float ps = 0.f;
#pragma unroll
        for (int kn = 0; kn < 4; ++kn) {
          const int kg = kb + kn * 16 + l15;
          const bool ok = (kg <= qg) && (kg > qg - WIN);
          const float p = ok ? __expf(fminf(s_acc[kn][reg], 34.f) - 34.f) : 0.f;
          ps += p;
          Ps[wave][r][kn * 16 + l15] = (__bf16)p;
        }
        l_run[reg] += ps;
      }
    }

    // O += P V   (Ps per-wave; intra-wave LDS ordering needs no barrier)
#pragma unroll
    for (int ks2 = 0; ks2 < 2; ++ks2) {
      bf16x8 pf = *(const bf16x8*)&Ps[wave][l15][ks2 * 32 + l4 * 8];
#pragma unroll
      for (int dn = 0; dn < 16; ++dn) {
        bf16x8 vf = *(const bf16x8*)&Vts2[ks2][dn * 16 + l15][l4 * 8];
        o[dn] = __builtin_amdgcn_mfma_f32_16x16x32_bf16(pf, vf, o[dn], 0, 0, 0);
      }
    }
  }

  // epilogue: reduce l across the 16 lanes sharing each row, then scale
#pragma unroll
  for (int reg = 0; reg < 4; ++reg) {
#pragma unroll
    for (int off = 1; off < 16; off <<= 1)
      l_run[reg] += __shfl_xor(l_run[reg], off);
    const float inv = 1.0f / l_run[reg];
    const int q = qw + l4 * 4 + reg;
    __bf16* yrow = Y + ((size_t)q * NH + head) * HD + l15;
#pragma unroll
    for (int dn = 0; dn < 16; ++dn)
      yrow[dn * 16] = (__bf16)(o[dn][reg] * inv);
  }
}

// ---------------------------------------------------------------------------
extern "C" void kernel_launch(void* const* d_in, const int* in_sizes, int n_in,
                              void* d_out, int out_size, void* d_ws, size_t ws_size,
                              hipStream_t stream) {
  (void)in_sizes; (void)n_in; (void)out_size; (void)ws_size;
  const float* x   = (const float*)d_in[0];
  const int*   pos = (const int*)d_in[1];
  const float* Wq  = (const float*)d_in[2];
  const float* Wk  = (const float*)d_in[3];
  const float* Wv  = (const float*)d_in[4];
  const float* Wo  = (const float*)d_in[5];
  const float* qw  = (const float*)d_in[6];
  const float* kw  = (const float*)d_in[7];
  float* out = (float*)d_out;

  char* ws = (char*)d_ws;
  const size_t MB = 1024 * 1024;
  __bf16* qkv_ws = (__bf16*)(ws);             // 32 MiB  [4096][4096] (V cols unused)
  __bf16* vt_ws  = (__bf16*)(ws + 32 * MB);   //  8 MiB  [4][256][4096]
  __bf16* y_ws   = (__bf16*)(ws + 40 * MB);   // 16 MiB  [4096][2048]
  __bf16* xb     = (__bf16*)(ws + 56 * MB);   // 16 MiB
  __bf16* wqkvb  = (__bf16*)(ws + 72 * MB);   // 16 MiB  [4096][2048]
  __bf16* wob    = (__bf16*)(ws + 88 * MB);   //  8 MiB  (total 96 MiB)

  cvt_all<<<dim3(2560), dim3(256), 0, stream>>>(x, Wq, Wk, Wv, Wo, xb, wqkvb, wob);
  gemm_bt<__bf16><<<dim3(32, 32), dim3(256), 0, stream>>>(xb, wqkvb, qkv_ws, vt_ws, 4096, 2048);
  norm_rope<<<dim3(3072), dim3(256), 0, stream>>>(qkv_ws, qw, kw, pos);
  attn_fwd<<<dim3(64, 8), dim3(256), 0, stream>>>(qkv_ws, vt_ws, y_ws);
  gemm_bt<float><<<dim3(32, 16), dim3(256), 0, stream>>>(y_ws, wob, out, (__bf16*)nullptr, 2048, 2048);
}

// Round 10
// 324.392 us; speedup vs baseline: 1.0029x; 1.0029x over previous
//
#include <hip/hip_runtime.h>
#include <cstdint>
#include <cmath>

typedef __bf16 bf16x8 __attribute__((ext_vector_type(8)));
typedef float  f32x4  __attribute__((ext_vector_type(4)));

#define DEVI __device__ __forceinline__

#define SEQ 4096
#define NH 8
#define NKV 4
#define HD 256
#define WIN 1024

DEVI void gload16(const void* g, void* l) {
  __builtin_amdgcn_global_load_lds((const __attribute__((address_space(1))) void*)g,
                                   (__attribute__((address_space(3))) void*)l,
                                   16, 0, 0);
}

DEVI bf16x8 ld8f(const float* p) {
  const f32x4 a = *(const f32x4*)p;
  const f32x4 b = *(const f32x4*)(p + 4);
  bf16x8 r;
#pragma unroll
  for (int j = 0; j < 4; ++j) { r[j] = (__bf16)a[j]; r[4 + j] = (__bf16)b[j]; }
  return r;
}

DEVI void st1(float* p, float v)  { *p = v; }
DEVI void st1(__bf16* p, float v) { *p = (__bf16)v; }

// ---------------------------------------------------------------------------
// fp32 -> bf16 conversion. Wq/Wk/Wv concatenated into one 4096x2048 buffer.
// ---------------------------------------------------------------------------
__global__ __launch_bounds__(256)
void cvt_all(const float* __restrict__ x,  const float* __restrict__ wq,
             const float* __restrict__ wk, const float* __restrict__ wv,
             const float* __restrict__ wo,
             __bf16* __restrict__ xb, __bf16* __restrict__ wqkvb,
             __bf16* __restrict__ wob) {
  const size_t g = (size_t)blockIdx.x * 256 + threadIdx.x;
  const float* src; __bf16* dst; size_t off;
  if      (g < 1048576) { src = x;  dst = xb;               off = g; }
  else if (g < 1572864) { src = wq; dst = wqkvb;            off = g - 1048576; }
  else if (g < 1835008) { src = wk; dst = wqkvb + 4194304;  off = g - 1572864; }
  else if (g < 2097152) { src = wv; dst = wqkvb + 6291456;  off = g - 1835008; }
  else                  { src = wo; dst = wob;              off = g - 2097152; }
  *(bf16x8*)(dst + off * 8) = ld8f(src + off * 8);
}

// ---------------------------------------------------------------------------
// GEMM: C[M][N] = A[M][K] * B[N][K]^T, bf16 in, f32 acc, BK=64 chunk-major
// (As2[2][128][32]: staging linear for global_load_lds, 64B fragment rows,
// 2-way conflict = free). Round-8 verified config: 904 TF.
// ---------------------------------------------------------------------------
template <typename TC>
__global__ __launch_bounds__(256, 2)
void gemm_bt(const __bf16* __restrict__ A, const __bf16* __restrict__ B,
             TC* __restrict__ C, int N, int K) {
  __shared__ __bf16 As2[2][128][32];   // 16 KB  [k-chunk][row][dim8]
  __shared__ __bf16 Bs2[2][128][32];   // 16 KB
  const int tid  = threadIdx.x;
  const int lane = tid & 63;
  const int wave = tid >> 6;
  const int l15  = lane & 15;
  const int l4   = lane >> 4;

  const int lin  = blockIdx.x + gridDim.x * blockIdx.y;
  const int xcd  = lin & 7;
  const int kk   = lin >> 3;
  const int row0 = (xcd * 4 + (kk & 3)) * 128;
  const int col0 = (kk >> 2) * 128;

  const int wm   = (wave >> 1) * 64;
  const int wn   = (wave & 1) * 64;

  f32x4 acc[4][4] = {};

  for (int k0 = 0; k0 < K; k0 += 64) {
    __syncthreads();
#pragma unroll
    for (int i = 0; i < 4; ++i) {
      const int s  = i * 256 + tid;
      const int ch = s >> 9, r = (s >> 2) & 127, c4 = s & 3;
      gload16(A + (size_t)(row0 + r) * K + k0 + ch * 32 + c4 * 8,
              (char*)As2 + (i * 256 + wave * 64) * 16);
    }
#pragma unroll
    for (int i = 0; i < 4; ++i) {
      const int s  = i * 256 + tid;
      const int ch = s >> 9, r = (s >> 2) & 127, c4 = s & 3;
      gload16(B + (size_t)(col0 + r) * K + k0 + ch * 32 + c4 * 8,
              (char*)Bs2 + (i * 256 + wave * 64) * 16);
    }
    __syncthreads();
#pragma unroll
    for (int ch = 0; ch < 2; ++ch) {
      bf16x8 af[4], bfr[4];
#pragma unroll
      for (int i = 0; i < 4; ++i)
        af[i] = *(const bf16x8*)&As2[ch][wm + i * 16 + l15][l4 * 8];
#pragma unroll
      for (int i = 0; i < 4; ++i)
        bfr[i] = *(const bf16x8*)&Bs2[ch][wn + i * 16 + l15][l4 * 8];
#pragma unroll
      for (int i = 0; i < 4; ++i)
#pragma unroll
        for (int j = 0; j < 4; ++j)
          acc[i][j] = __builtin_amdgcn_mfma_f32_16x16x32_bf16(af[i], bfr[j], acc[i][j], 0, 0, 0);
    }
  }

  // C/D layout: col = lane&15, row = (lane>>4)*4 + reg   [m89/m91 verified]
#pragma unroll
  for (int i = 0; i < 4; ++i) {
#pragma unroll
    for (int reg = 0; reg < 4; ++reg) {
      const int row = row0 + wm + i * 16 + l4 * 4 + reg;
      TC* crow = C + (size_t)row * N + col0 + wn + l15;
#pragma unroll
      for (int j = 0; j < 4; ++j)
        st1(crow + j * 16, acc[i][j][reg]);
    }
  }
}

// ---------------------------------------------------------------------------
// Merged: per-head RMSNorm+RoPE (blocks 0..12287) and V-transpose (12288+).
// ---------------------------------------------------------------------------
__global__ __launch_bounds__(256)
void norm_rope_tv(__bf16* __restrict__ qkv, __bf16* __restrict__ Vt,
                  const float* __restrict__ qw, const float* __restrict__ kw,
                  const int* __restrict__ pos) {
  if (blockIdx.x < 12288) {
    const int gw   = blockIdx.x * 4 + (threadIdx.x >> 6);
    const int lane = threadIdx.x & 63;
    __bf16* base; const float* w; int t;
    if (gw < SEQ * NH) {
      t = gw >> 3;
      base = qkv + (size_t)t * 4096 + (gw & 7) * HD;
      w = qw;
    } else {
      const int g = gw - SEQ * NH;
      t = g >> 2;
      base = qkv + (size_t)t * 4096 + 2048 + (g & 3) * HD;
      w = kw;
    }

    const int d0 = lane * 4;
    float v[4]; float ss = 0.f;
#pragma unroll
    for (int j = 0; j < 4; ++j) { v[j] = (float)base[d0 + j]; ss += v[j] * v[j]; }
#pragma unroll
    for (int off = 1; off < 64; off <<= 1) ss += __shfl_xor(ss, off);
    const float rms = rsqrtf(ss * (1.0f / 256.0f) + 1e-6f);
    const float p = (float)pos[t];

    float n[4];
#pragma unroll
    for (int j = 0; j < 4; ++j) n[j] = v[j] * rms * w[d0 + j];

    float outv[4];
#pragma unroll
    for (int e = 0; e < 4; e += 2) {
      const int i0 = d0 + e, i1 = i0 + 1;
      const float f0 = exp2f(-(float)(i0 & 127) * 0.103810253f);
      const float f1 = exp2f(-(float)(i1 & 127) * 0.103810253f);
      float s0, cc0, s1, cc1;
      sincosf(p * f0, &s0, &cc0);
      sincosf(p * f1, &s1, &cc1);
      outv[e]     = n[e] * cc0 - n[e + 1] * s0;
      outv[e + 1] = n[e + 1] * cc1 + n[e] * s1;
    }
#pragma unroll
    for (int j = 0; j < 4; ++j) base[d0 + j] = (__bf16)outv[j];
  } else {
    __shared__ __bf16 tile[64][72];
    const int b   = blockIdx.x - 12288;       // 0..1023
    const int tid = threadIdx.x;
    const int tb  = (b & 63) * 64;
    const int yy  = b >> 6;                   // 0..15
    const int kvh = yy >> 2;
    const int db  = (yy & 3) * 64;
#pragma unroll
    for (int i = 0; i < 2; ++i) {
      const int s = i * 256 + tid;
      const int r = s >> 3, c = (s & 7) * 8;
      bf16x8 val = *(const bf16x8*)(qkv + (size_t)(tb + r) * 4096 + 3072 + kvh * HD + db + c);
#pragma unroll
      for (int j = 0; j < 8; ++j) tile[r][c + j] = val[j];
    }
    __syncthreads();
#pragma unroll
    for (int i = 0; i < 2; ++i) {
      const int s = i * 256 + tid;
      const int r = s >> 3, c = (s & 7) * 8;
      bf16x8 outv;
#pragma unroll
      for (int j = 0; j < 8; ++j) outv[j] = tile[c + j][r];
      *(bf16x8*)(Vt + (size_t)(kvh * HD + db + r) * SEQ + tb + c) = outv;
    }
  }
}

// ---------------------------------------------------------------------------
// Sliding-window flash attention, fixed-max softmax, async LDS staging.
// Grid (8 heads, 64 q-tiles): linear id = head + 8*qt => XCD = head, so each
// XCD's L2 holds exactly one kvh's K+V slice (4 MB) — L2-resident.
// ---------------------------------------------------------------------------
__global__ __launch_bounds__(256, 2)
void attn_fwd(const __bf16* __restrict__ qkv, const __bf16* __restrict__ Vt,
              __bf16* __restrict__ Y) {
  __shared__ __bf16 Ks2[8][64][32];    // 32768 B  [k-chunk][key][dim8]
  __shared__ __bf16 Vts2[2][256][32];  // 32768 B  [key-chunk][dim][key8]
  __shared__ __bf16 Ps[4][16][72];     //  9216 B  per-wave P
  const int tid  = threadIdx.x;
  const int lane = tid & 63;
  const int wave = tid >> 6;
  const int l15  = lane & 15;
  const int l4   = lane >> 4;
  const int head = blockIdx.x;          // grid.x = 8 -> XCD = head
  const int q0   = blockIdx.y * 64;
  const int kvh  = head >> 1;
  const int qw   = q0 + wave * 16;

  // Q fragments: A[m=lane&15][k=(lane>>4)*8+j]; pre-scale 1/16 (exact pow2)
  bf16x8 qf[8];
  const __bf16* qrow = qkv + (size_t)(qw + l15) * 4096 + head * HD;
#pragma unroll
  for (int ks = 0; ks < 8; ++ks) {
    bf16x8 t = *(const bf16x8*)(qrow + ks * 32 + l4 * 8);
#pragma unroll
    for (int j = 0; j < 8; ++j) t[j] = (__bf16)((float)t[j] * 0.0625f);
    qf[ks] = t;
  }

  f32x4 o[16] = {};
  float l_run[4] = {0.f, 0.f, 0.f, 0.f};

  int lo = q0 - (WIN - 1); if (lo < 0) lo = 0;
  const int kt0 = lo >> 6;
  const int kt1 = (q0 + 63) >> 6;   // uniform across the block

  for (int kt = kt0; kt <= kt1; ++kt) {
    const int kb = kt * 64;
    __syncthreads();
#pragma unroll
    for (int i = 0; i < 8; ++i) {
      const int s = i * 256 + tid;
      gload16(qkv + (size_t)(kb + ((s >> 2) & 63)) * 4096 + 2048 + kvh * HD
                  + (s >> 8) * 32 + (s & 3) * 8,
              (char*)Ks2 + (i * 256 + wave * 64) * 16);
    }
#pragma unroll
    for (int i = 0; i < 8; ++i) {
      const int s = i * 256 + tid;
      gload16(Vt + ((size_t)kvh * HD + ((s >> 2) & 255)) * SEQ + kb
                 + (s >> 10) * 32 + (s & 3) * 8,
              (char*)Vts2 + (i * 256 + wave * 64) * 16);
    }
    __syncthreads();

    // S = (Q/16) K^T
    f32x4 s_acc[4] = {};
#pragma unroll
    for (int kn = 0; kn < 4; ++kn) {
#pragma unroll
      for (int ks = 0; ks < 8; ++ks) {
        bf16x8 kf = *(const bf16x8*)&Ks2[ks][kn * 16 + l15][l4 * 8];
        s_acc[kn] = __builtin_amdgcn_mfma_f32_16x16x32_bf16(qf[ks], kf, s_acc[kn], 0, 0, 0);
      }
    }

    // fixed-max softmax: p = exp(min(s,34)-34); masked -> 0
    // (post-RMSNorm |q|=|k|=16, RoPE growth <= sqrt2 => s <= 32 provably)
    // Wave-uniform fast path when the whole tile is visible to all 16 rows.
    const bool allvis = (kb + 63 <= qw) && (kb >= qw - 1008);
    if (allvis) {
#pragma unroll
      for (int reg = 0; reg < 4; ++reg) {
        const int r = l4 * 4 + reg;
        float ps = 0.f;
#pragma unroll
        for (int kn = 0; kn < 4; ++kn) {
          const float p = __expf(fminf(s_acc[kn][reg], 34.f) - 34.f);
          ps += p;
          Ps[wave][r][kn * 16 + l15] = (__bf16)p;
        }
        l_run[reg] += ps;
      }
    } else {
#pragma unroll
      for (int reg = 0; reg < 4; ++reg) {
        const int r  = l4 * 4 + reg;
        const int qg = qw + r;
        float ps = 0.f;
#pragma unroll
        for (int kn = 0; kn < 4; ++kn) {
          const int kg = kb + kn * 16 + l15;
          const bool ok = (kg <= qg) && (kg > qg - WIN);
          const float p = ok ? __expf(fminf(s_acc[kn][reg], 34.f) - 34.f) : 0.f;
          ps += p;
          Ps[wave][r][kn * 16 + l15] = (__bf16)p;
        }
        l_run[reg] += ps;
      }
    }

    // O += P V   (Ps per-wave; intra-wave LDS ordering needs no barrier)
#pragma unroll
    for (int ks2 = 0; ks2 < 2; ++ks2) {
      bf16x8 pf = *(const bf16x8*)&Ps[wave][l15][ks2 * 32 + l4 * 8];
#pragma unroll
      for (int dn = 0; dn < 16; ++dn) {
        bf16x8 vf = *(const bf16x8*)&Vts2[ks2][dn * 16 + l15][l4 * 8];
        o[dn] = __builtin_amdgcn_mfma_f32_16x16x32_bf16(pf, vf, o[dn], 0, 0, 0);
      }
    }
  }

  // epilogue: reduce l across the 16 lanes sharing each row, then scale
#pragma unroll
  for (int reg = 0; reg < 4; ++reg) {
#pragma unroll
    for (int off = 1; off < 16; off <<= 1)
      l_run[reg] += __shfl_xor(l_run[reg], off);
    const float inv = 1.0f / l_run[reg];
    const int q = qw + l4 * 4 + reg;
    __bf16* yrow = Y + ((size_t)q * NH + head) * HD + l15;
#pragma unroll
    for (int dn = 0; dn < 16; ++dn)
      yrow[dn * 16] = (__bf16)(o[dn][reg] * inv);
  }
}

// ---------------------------------------------------------------------------
extern "C" void kernel_launch(void* const* d_in, const int* in_sizes, int n_in,
                              void* d_out, int out_size, void* d_ws, size_t ws_size,
                              hipStream_t stream) {
  (void)in_sizes; (void)n_in; (void)out_size; (void)ws_size;
  const float* x   = (const float*)d_in[0];
  const int*   pos = (const int*)d_in[1];
  const float* Wq  = (const float*)d_in[2];
  const float* Wk  = (const float*)d_in[3];
  const float* Wv  = (const float*)d_in[4];
  const float* Wo  = (const float*)d_in[5];
  const float* qw  = (const float*)d_in[6];
  const float* kw  = (const float*)d_in[7];
  float* out = (float*)d_out;

  char* ws = (char*)d_ws;
  const size_t MB = 1024 * 1024;
  __bf16* qkv_ws = (__bf16*)(ws);             // 32 MiB  [4096][4096]
  __bf16* vt_ws  = (__bf16*)(ws + 32 * MB);   //  8 MiB  [4][256][4096]
  __bf16* y_ws   = (__bf16*)(ws + 40 * MB);   // 16 MiB  [4096][2048]
  __bf16* xb     = (__bf16*)(ws + 56 * MB);   // 16 MiB
  __bf16* wqkvb  = (__bf16*)(ws + 72 * MB);   // 16 MiB  [4096][2048]
  __bf16* wob    = (__bf16*)(ws + 88 * MB);   //  8 MiB  (total 96 MiB)

  cvt_all<<<dim3(10240), dim3(256), 0, stream>>>(x, Wq, Wk, Wv, Wo, xb, wqkvb, wob);
  gemm_bt<__bf16><<<dim3(32, 32), dim3(256), 0, stream>>>(xb, wqkvb, qkv_ws, 4096, 2048);
  norm_rope_tv<<<dim3(13312), dim3(256), 0, stream>>>(qkv_ws, vt_ws, qw, kw, pos);
  attn_fwd<<<dim3(8, 64), dim3(256), 0, stream>>>(qkv_ws, vt_ws, y_ws);
  gemm_bt<float><<<dim3(32, 16), dim3(256), 0, stream>>>(y_ws, wob, out, 2048, 2048);
}